// Round 1
// baseline (435.777 us; speedup 1.0000x reference)
//
#include <hip/hip_runtime.h>
#include <math.h>

#define N 1024
#define LOGN 10
#define BATCH 32
#define NTHREADS 256

// ---------------------------------------------------------------------------
// In-place 1024-point radix-2 DIT FFT on LDS. tw[j] = exp(-2*pi*i*j/N), j<512.
// Begins with a barrier (callers write the buffer right before).
// ---------------------------------------------------------------------------
__device__ __forceinline__ void fft1024(float2* sh, const float2* tw, bool inv, int tid) {
    __syncthreads();
    // bit-reverse permutation (each swap pair handled by exactly one thread)
    for (int i = tid; i < N; i += NTHREADS) {
        int j = (int)(__brev((unsigned)i) >> (32 - LOGN));
        if (j > i) { float2 t = sh[i]; sh[i] = sh[j]; sh[j] = t; }
    }
    __syncthreads();
    for (int s = 1; s <= LOGN; ++s) {
        int half = 1 << (s - 1);
        for (int t = tid; t < (N >> 1); t += NTHREADS) {
            int j = t & (half - 1);
            int base = (t >> (s - 1)) << s;
            float2 w = tw[j << (LOGN - s)];
            float wy = inv ? -w.y : w.y;
            float2 u = sh[base + j];
            float2 v = sh[base + j + half];
            float vr = v.x * w.x - v.y * wy;
            float vi = v.x * wy + v.y * w.x;
            sh[base + j]        = make_float2(u.x + vr, u.y + vi);
            sh[base + j + half] = make_float2(u.x - vr, u.y - vi);
        }
        __syncthreads();
    }
}

// ---------------------------------------------------------------------------
// Precompute twiddle table (512) and SHIFT_FACTOR table (1024) into ws.
// SF[n] = exp(-i * p), p = (float)(2*W_CENTER*DELTA_TAU*(n-512)) = 3.525*(n-512)
// ---------------------------------------------------------------------------
__global__ void init_tables(float2* __restrict__ tw, float2* __restrict__ sf) {
    int i = blockIdx.x * blockDim.x + threadIdx.x;
    if (i < N / 2) {
        float ang = (float)(-6.283185307179586 * (double)i / (double)N);
        float s, c;
        sincosf(ang, &s, &c);
        tw[i] = make_float2(c, s);
    }
    if (i < N) {
        float p = (float)(3.525 * (double)(i - N / 2));
        float s, c;
        sincosf(p, &s, &c);
        sf[i] = make_float2(c, -s);
    }
}

// ---------------------------------------------------------------------------
// Kernel 1: analytic signal a = ifft(fft(x) * mask), mask = [0]*512,[1],[2]*511
// ---------------------------------------------------------------------------
__global__ __launch_bounds__(NTHREADS) void hilbert_k(const float* __restrict__ pred,
                                                      const float2* __restrict__ twg,
                                                      float2* __restrict__ a) {
    __shared__ float2 sh[N];
    __shared__ float2 tw[N / 2];
    int tid = threadIdx.x, b = blockIdx.x;
    for (int i = tid; i < N / 2; i += NTHREADS) tw[i] = twg[i];
    for (int i = tid; i < N; i += NTHREADS) sh[i] = make_float2(pred[b * N + i], 0.f);
    fft1024(sh, tw, false, tid);
    for (int i = tid; i < N; i += NTHREADS) {
        if (i < N / 2) sh[i] = make_float2(0.f, 0.f);
        else if (i > N / 2) { sh[i].x *= 2.f; sh[i].y *= 2.f; }
    }
    fft1024(sh, tw, true, tid);
    const float sc = 1.f / (float)N;
    for (int i = tid; i < N; i += NTHREADS)
        a[b * N + i] = make_float2(sh[i].x * sc, sh[i].y * sc);
}

// ---------------------------------------------------------------------------
// Kernel 2: one block per (b, d). row[n] = a[n]*a[(n-delay)%N]*SF[n];
// F = fft(fftshift(row)); raw[k] = |F[(k+512)%N]|^2 (DELTA_TAU^2 dropped —
// it cancels under max-normalization). Emit per-row partials:
// sum(raw), sum(raw*t), max(raw), sum(t), sum(t^2).
// ---------------------------------------------------------------------------
__global__ __launch_bounds__(NTHREADS) void shg_k(const float2* __restrict__ a,
                                                  const float* __restrict__ tref,
                                                  const float2* __restrict__ twg,
                                                  const float2* __restrict__ sfg,
                                                  float* __restrict__ Praw,
                                                  float* __restrict__ Prt,
                                                  float* __restrict__ Pmax,
                                                  float* __restrict__ Pt,
                                                  float* __restrict__ Ptt) {
    __shared__ float2 sha[N];
    __shared__ float2 shf[N];
    __shared__ float2 tw[N / 2];
    __shared__ float rbuf[4][8];
    int tid = threadIdx.x;
    int bd = blockIdx.x;
    int b = bd >> LOGN, d = bd & (N - 1);
    for (int i = tid; i < N / 2; i += NTHREADS) tw[i] = twg[i];
    for (int i = tid; i < N; i += NTHREADS) sha[i] = a[b * N + i];
    __syncthreads();
    int delay = d - N / 2;
    for (int n = tid; n < N; n += NTHREADS) {
        float2 x = sha[n];
        float2 y = sha[(n - delay) & (N - 1)];
        float pr = x.x * y.x - x.y * y.y;
        float pi = x.x * y.y + x.y * y.x;
        float2 w = sfg[n];
        float rr = pr * w.x - pi * w.y;
        float ri = pr * w.y + pi * w.x;
        shf[(n + N / 2) & (N - 1)] = make_float2(rr, ri);
    }
    fft1024(shf, tw, false, tid);
    float sraw = 0.f, srt = 0.f, mx = 0.f, st = 0.f, stt = 0.f;
    const float* trow = tref + ((size_t)bd << LOGN);
    for (int k = tid; k < N; k += NTHREADS) {
        float2 F = shf[k];
        float m2 = F.x * F.x + F.y * F.y;
        float tv = trow[(k + N / 2) & (N - 1)];
        sraw += m2;
        srt += m2 * tv;
        mx = fmaxf(mx, m2);
        st += tv;
        stt += tv * tv;
    }
    for (int o = 32; o > 0; o >>= 1) {
        sraw += __shfl_down(sraw, o);
        srt  += __shfl_down(srt, o);
        mx    = fmaxf(mx, __shfl_down(mx, o));
        st   += __shfl_down(st, o);
        stt  += __shfl_down(stt, o);
    }
    int w = tid >> 6, lane = tid & 63;
    if (lane == 0) {
        rbuf[w][0] = sraw; rbuf[w][1] = srt; rbuf[w][2] = mx;
        rbuf[w][3] = st;   rbuf[w][4] = stt;
    }
    __syncthreads();
    if (tid == 0) {
        float a0 = 0.f, a1 = 0.f, a2 = 0.f, a3 = 0.f, a4 = 0.f;
        for (int i = 0; i < 4; ++i) {
            a0 += rbuf[i][0]; a1 += rbuf[i][1]; a2 = fmaxf(a2, rbuf[i][2]);
            a3 += rbuf[i][3]; a4 += rbuf[i][4];
        }
        Praw[bd] = a0; Prt[bd] = a1; Pmax[bd] = a2; Pt[bd] = a3; Ptt[bd] = a4;
    }
}

// ---------------------------------------------------------------------------
// Kernel 3: per batch — reduce row partials -> frog; label scan -> first/last;
// masked MSE terms; atomicAdd mean contribution into out[0].
// ---------------------------------------------------------------------------
__global__ __launch_bounds__(NTHREADS) void loss_k(const float2* __restrict__ a,
                                                   const float* __restrict__ label,
                                                   const float* __restrict__ Praw,
                                                   const float* __restrict__ Prt,
                                                   const float* __restrict__ Pmax,
                                                   const float* __restrict__ Pt,
                                                   const float* __restrict__ Ptt,
                                                   float* __restrict__ out) {
    __shared__ float rbuf[4][8];
    __shared__ int ibuf[4][4];
    __shared__ int s_first, s_last;
    int tid = threadIdx.x, b = blockIdx.x;
    int w = tid >> 6, lane = tid & 63;

    // ---- phase A: frog scalars ----
    float sr = 0.f, srt = 0.f, mx = 0.f, st = 0.f, stt = 0.f;
    for (int i = tid; i < N; i += NTHREADS) {
        int idx = b * N + i;
        sr += Praw[idx]; srt += Prt[idx]; mx = fmaxf(mx, Pmax[idx]);
        st += Pt[idx];   stt += Ptt[idx];
    }
    for (int o = 32; o > 0; o >>= 1) {
        sr  += __shfl_down(sr, o);
        srt += __shfl_down(srt, o);
        mx   = fmaxf(mx, __shfl_down(mx, o));
        st  += __shfl_down(st, o);
        stt += __shfl_down(stt, o);
    }
    if (lane == 0) {
        rbuf[w][0] = sr; rbuf[w][1] = srt; rbuf[w][2] = mx;
        rbuf[w][3] = st; rbuf[w][4] = stt;
    }
    __syncthreads();
    float frog = 0.f;
    if (tid == 0) {
        float A0 = 0.f, A1 = 0.f, A2 = 0.f, A3 = 0.f, A4 = 0.f;
        for (int i = 0; i < 4; ++i) {
            A0 += rbuf[i][0]; A1 += rbuf[i][1]; A2 = fmaxf(A2, rbuf[i][2]);
            A3 += rbuf[i][3]; A4 += rbuf[i][4];
        }
        float mu = (A1 / A2) / A4;            // (S_rt / M) / S_tt
        float diff = A0 / A2 - mu * A3;       // S_raw/M - mu*S_t
        frog = fabsf(diff) * (1.f / (float)N); // sqrt(diff^2 / N^2)
    }

    // ---- phase B: first/last from label masks ----
    int mnR = N, mxR = -1, mnI = N, mxI = -1;
    for (int n = tid; n < N; n += NTHREADS) {
        float lr = label[b * 2 * N + n];
        float li = label[b * 2 * N + N + n];
        if (fabsf(lr) > 0.01f) { mnR = min(mnR, n); mxR = max(mxR, n); }
        if (fabsf(li) > 0.01f) { mnI = min(mnI, n); mxI = max(mxI, n); }
    }
    for (int o = 32; o > 0; o >>= 1) {
        mnR = min(mnR, __shfl_down(mnR, o));
        mxR = max(mxR, __shfl_down(mxR, o));
        mnI = min(mnI, __shfl_down(mnI, o));
        mxI = max(mxI, __shfl_down(mxI, o));
    }
    if (lane == 0) { ibuf[w][0] = mnR; ibuf[w][1] = mxR; ibuf[w][2] = mnI; ibuf[w][3] = mxI; }
    __syncthreads();
    if (tid == 0) {
        int a0 = N, a1 = -1, a2 = N, a3 = -1;
        for (int i = 0; i < 4; ++i) {
            a0 = min(a0, ibuf[i][0]); a1 = max(a1, ibuf[i][1]);
            a2 = min(a2, ibuf[i][2]); a3 = max(a3, ibuf[i][3]);
        }
        int fr  = (a0 == N) ? 0 : a0;
        int lstR = (a1 < 0) ? (N - 1) : a1;
        int fi  = (a2 == N) ? 0 : a2;
        int lstI = (a3 < 0) ? (N - 1) : a3;
        s_first = min(fr, fi);
        s_last  = max(lstR, lstI);
    }
    __syncthreads();
    int first = s_first, last = s_last;

    // ---- phase C: masked MSE terms ----
    float m_r = 0.f, m_i = 0.f, m_n = 0.f, m_p = 0.f;
    for (int n = tid; n < N; n += NTHREADS) {
        float2 p = a[b * N + n];
        float lr = label[b * 2 * N + n];
        float li = label[b * 2 * N + N + n];
        bool in = (n >= first) && (n < last);
        float pm  = in ? 10.f : 1.f;
        float phm = in ? 1.f : 0.f;
        float dr = p.x - lr, di = p.y - li;
        float pint = p.x * p.x + p.y * p.y;
        float lint = lr * lr + li * li;
        float dn = pint - lint;
        float dp = atan2f(p.y, p.x) - atan2f(li, lr);
        m_r += dr * dr * pm;
        m_i += di * di * pm;
        m_n += dn * dn * pm;
        m_p += dp * dp * phm;
    }
    for (int o = 32; o > 0; o >>= 1) {
        m_r += __shfl_down(m_r, o);
        m_i += __shfl_down(m_i, o);
        m_n += __shfl_down(m_n, o);
        m_p += __shfl_down(m_p, o);
    }
    if (lane == 0) { rbuf[w][0] = m_r; rbuf[w][1] = m_i; rbuf[w][2] = m_n; rbuf[w][3] = m_p; }
    __syncthreads();
    if (tid == 0) {
        float t0 = 0.f, t1 = 0.f, t2 = 0.f, t3 = 0.f;
        for (int i = 0; i < 4; ++i) {
            t0 += rbuf[i][0]; t1 += rbuf[i][1]; t2 += rbuf[i][2]; t3 += rbuf[i][3];
        }
        float mse = (t0 + t1 + t2 + t3) * (1.f / (float)N) * 0.25f;
        atomicAdd(out, (mse + frog) * (1.f / (float)BATCH));
    }
}

extern "C" void kernel_launch(void* const* d_in, const int* in_sizes, int n_in,
                              void* d_out, int out_size, void* d_ws, size_t ws_size,
                              hipStream_t stream) {
    (void)in_sizes; (void)n_in; (void)out_size; (void)ws_size;
    const float* pred  = (const float*)d_in[0];
    const float* label = (const float*)d_in[1];
    const float* shg   = (const float*)d_in[2];
    float* out = (float*)d_out;

    char* ws = (char*)d_ws;
    float2* a  = (float2*)ws;                                         // B*N complex  (256 KB)
    float2* tw = (float2*)(ws + (size_t)BATCH * N * sizeof(float2));  // 512          (4 KB)
    float2* sf = (float2*)((char*)tw + 512 * sizeof(float2));         // 1024         (8 KB)
    float*  P  = (float*)((char*)sf + 1024 * sizeof(float2));         // 5 * B*N      (640 KB)
    float* Praw = P;
    float* Prt  = P + (size_t)BATCH * N;
    float* Pmax = P + 2 * (size_t)BATCH * N;
    float* Pt   = P + 3 * (size_t)BATCH * N;
    float* Ptt  = P + 4 * (size_t)BATCH * N;

    hipMemsetAsync(d_out, 0, sizeof(float), stream);
    init_tables<<<4, 256, 0, stream>>>(tw, sf);
    hilbert_k<<<BATCH, NTHREADS, 0, stream>>>(pred, tw, a);
    shg_k<<<BATCH * N, NTHREADS, 0, stream>>>(a, shg, tw, sf, Praw, Prt, Pmax, Pt, Ptt);
    loss_k<<<BATCH, NTHREADS, 0, stream>>>(a, label, Praw, Prt, Pmax, Pt, Ptt, out);
}

// Round 2
// 312.295 us; speedup vs baseline: 1.3954x; 1.3954x over previous
//
#include <hip/hip_runtime.h>
#include <math.h>

#define N 1024
#define LOGN 10
#define BATCH 32
#define NTHREADS 256
// pad one float per 32 to break power-of-2 bank strides
#define PADF(i) ((i) + ((i) >> 5))

// ---------------------------------------------------------------------------
// Radix-4 DIF butterfly with twiddles w^p, w = exp(-2*pi*i/n), ps = p*s so
// that p/n == ps/1024.  sincospif(ps/512) gives sin/cos(2*pi*ps/1024).
// ---------------------------------------------------------------------------
__device__ __forceinline__ void bfly4(float ar, float ai, float br, float bi,
                                      float cr, float ci, float dr, float di,
                                      int ps, float* yr, float* yi) {
    float apc_r = ar + cr, apc_i = ai + ci;
    float amc_r = ar - cr, amc_i = ai - ci;
    float bpd_r = br + dr, bpd_i = bi + di;
    float bmd_r = br - dr, bmd_i = bi - di;
    yr[0] = apc_r + bpd_r; yi[0] = apc_i + bpd_i;
    // t1 = amc - i*bmd ; t2 = apc - bpd ; t3 = amc + i*bmd
    float t1r = amc_r + bmd_i, t1i = amc_i - bmd_r;
    float t2r = apc_r - bpd_r, t2i = apc_i - bpd_i;
    float t3r = amc_r - bmd_i, t3i = amc_i + bmd_r;
    float sn, cs;
    sincospif((float)ps * (1.0f / 512.0f), &sn, &cs);
    float w1r = cs, w1i = -sn;
    float w2r = w1r * w1r - w1i * w1i, w2i = 2.0f * w1r * w1i;
    float w3r = w2r * w1r - w2i * w1i, w3i = w2r * w1i + w2i * w1r;
    yr[1] = w1r * t1r - w1i * t1i; yi[1] = w1r * t1i + w1i * t1r;
    yr[2] = w2r * t2r - w2i * t2i; yi[2] = w2r * t2i + w2i * t2r;
    yr[3] = w3r * t3r - w3i * t3i; yi[3] = w3r * t3i + w3i * t3r;
}

// Stockham stage: reads x at {t, t+256, t+512, t+768}, writes y at
// q + s*(4p+k), with t = p*s + q.  One radix-4 butterfly per thread.
template <int LOG2S>
__device__ __forceinline__ void stage_t(const float* xre, const float* xim,
                                        float* yre, float* yim, int t) {
    const int s = 1 << LOG2S;
    float ar = xre[PADF(t)],       ai = xim[PADF(t)];
    float br = xre[PADF(t + 256)], bi = xim[PADF(t + 256)];
    float cr = xre[PADF(t + 512)], ci = xim[PADF(t + 512)];
    float dr = xre[PADF(t + 768)], di = xim[PADF(t + 768)];
    float yr[4], yi[4];
    bfly4(ar, ai, br, bi, cr, ci, dr, di, t & ~(s - 1), yr, yi);
    int w0 = (t & (s - 1)) + ((t >> LOG2S) << (LOG2S + 2));
#pragma unroll
    for (int k = 0; k < 4; ++k) {
        int o = PADF(w0 + k * s);
        yre[o] = yr[k];
        yim[o] = yi[k];
    }
}

// ---------------------------------------------------------------------------
// Legacy radix-2 in-place FFT (used only by hilbert_k, 32 blocks — cheap).
// ---------------------------------------------------------------------------
__device__ __forceinline__ void fft1024(float2* sh, const float2* tw, bool inv, int tid) {
    __syncthreads();
    for (int i = tid; i < N; i += NTHREADS) {
        int j = (int)(__brev((unsigned)i) >> (32 - LOGN));
        if (j > i) { float2 t = sh[i]; sh[i] = sh[j]; sh[j] = t; }
    }
    __syncthreads();
    for (int s = 1; s <= LOGN; ++s) {
        int half = 1 << (s - 1);
        for (int t = tid; t < (N >> 1); t += NTHREADS) {
            int j = t & (half - 1);
            int base = (t >> (s - 1)) << s;
            float2 w = tw[j << (LOGN - s)];
            float wy = inv ? -w.y : w.y;
            float2 u = sh[base + j];
            float2 v = sh[base + j + half];
            float vr = v.x * w.x - v.y * wy;
            float vi = v.x * wy + v.y * w.x;
            sh[base + j]        = make_float2(u.x + vr, u.y + vi);
            sh[base + j + half] = make_float2(u.x - vr, u.y - vi);
        }
        __syncthreads();
    }
}

__global__ void init_tables(float2* __restrict__ tw, float2* __restrict__ sf) {
    int i = blockIdx.x * blockDim.x + threadIdx.x;
    if (i < N / 2) {
        float ang = (float)(-6.283185307179586 * (double)i / (double)N);
        float s, c;
        sincosf(ang, &s, &c);
        tw[i] = make_float2(c, s);
    }
    if (i < N) {
        float p = (float)(3.525 * (double)(i - N / 2));
        float s, c;
        sincosf(p, &s, &c);
        sf[i] = make_float2(c, -s);
    }
}

__global__ __launch_bounds__(NTHREADS) void hilbert_k(const float* __restrict__ pred,
                                                      const float2* __restrict__ twg,
                                                      float2* __restrict__ a) {
    __shared__ float2 sh[N];
    __shared__ float2 tw[N / 2];
    int tid = threadIdx.x, b = blockIdx.x;
    for (int i = tid; i < N / 2; i += NTHREADS) tw[i] = twg[i];
    for (int i = tid; i < N; i += NTHREADS) sh[i] = make_float2(pred[b * N + i], 0.f);
    fft1024(sh, tw, false, tid);
    for (int i = tid; i < N; i += NTHREADS) {
        if (i < N / 2) sh[i] = make_float2(0.f, 0.f);
        else if (i > N / 2) { sh[i].x *= 2.f; sh[i].y *= 2.f; }
    }
    fft1024(sh, tw, true, tid);
    const float sc = 1.f / (float)N;
    for (int i = tid; i < N; i += NTHREADS)
        a[b * N + i] = make_float2(sh[i].x * sc, sh[i].y * sc);
}

// ---------------------------------------------------------------------------
// shg_k: one block per (b, d).  Radix-4 Stockham, stage-1 fused with the row
// product (fftshift folded into the index), stage-5 fused with the reduction.
// ---------------------------------------------------------------------------
__global__ __launch_bounds__(NTHREADS) void shg_k(const float2* __restrict__ a,
                                                  const float* __restrict__ tref,
                                                  const float2* __restrict__ sfg,
                                                  float* __restrict__ Praw,
                                                  float* __restrict__ Prt,
                                                  float* __restrict__ Pmax,
                                                  float* __restrict__ Pt,
                                                  float* __restrict__ Ptt) {
    __shared__ float2 sha[N];
    __shared__ float Are[1056], Aim[1056], Bre[1056], Bim[1056];
    __shared__ float rbuf[4][8];
    int t = threadIdx.x;
    int bd = blockIdx.x;
    int b = bd >> LOGN, d = bd & (N - 1);
    int delay = d - N / 2;

    for (int i = t; i < N; i += NTHREADS) sha[i] = a[b * N + i];
    __syncthreads();

    // ---- stage 1 (n=1024, s=1): inputs computed on the fly ----
    {
        float vr[4], vi[4];
#pragma unroll
        for (int k = 0; k < 4; ++k) {
            int n = (t + 256 * k + 512) & (N - 1);     // fftshift
            float2 x = sha[n];
            float2 y = sha[(n - delay) & (N - 1)];
            float pr = x.x * y.x - x.y * y.y;
            float pi = x.x * y.y + x.y * y.x;
            float2 w = sfg[n];
            vr[k] = pr * w.x - pi * w.y;
            vi[k] = pr * w.y + pi * w.x;
        }
        float yr[4], yi[4];
        bfly4(vr[0], vi[0], vr[1], vi[1], vr[2], vi[2], vr[3], vi[3], t, yr, yi);
#pragma unroll
        for (int k = 0; k < 4; ++k) {
            int o = PADF(4 * t + k);
            Are[o] = yr[k];
            Aim[o] = yi[k];
        }
    }
    __syncthreads();
    stage_t<2>(Are, Aim, Bre, Bim, t);   // n=256,  s=4
    __syncthreads();
    stage_t<4>(Bre, Bim, Are, Aim, t);   // n=64,   s=16
    __syncthreads();
    stage_t<6>(Are, Aim, Bre, Bim, t);   // n=16,   s=64
    __syncthreads();

    // ---- stage 5 (n=4, s=256, p=0: unit twiddles) fused with reduction ----
    float sraw = 0.f, srt = 0.f, mx = 0.f, st = 0.f, stt = 0.f;
    const float* trow = tref + ((size_t)bd << LOGN);
    {
        float ar = Bre[PADF(t)],       ai = Bim[PADF(t)];
        float br = Bre[PADF(t + 256)], bi = Bim[PADF(t + 256)];
        float cr = Bre[PADF(t + 512)], ci = Bim[PADF(t + 512)];
        float dr = Bre[PADF(t + 768)], di = Bim[PADF(t + 768)];
        float apc_r = ar + cr, apc_i = ai + ci;
        float amc_r = ar - cr, amc_i = ai - ci;
        float bpd_r = br + dr, bpd_i = bi + di;
        float bmd_r = br - dr, bmd_i = bi - di;
        float yr[4], yi[4];
        yr[0] = apc_r + bpd_r; yi[0] = apc_i + bpd_i;
        yr[1] = amc_r + bmd_i; yi[1] = amc_i - bmd_r;
        yr[2] = apc_r - bpd_r; yi[2] = apc_i - bpd_i;
        yr[3] = amc_r - bmd_i; yi[3] = amc_i + bmd_r;
#pragma unroll
        for (int k = 0; k < 4; ++k) {
            int o = t + 256 * k;                       // natural-order output
            float m2 = yr[k] * yr[k] + yi[k] * yi[k];
            float tv = trow[(o + 512) & (N - 1)];      // output fftshift pairing
            sraw += m2;
            srt += m2 * tv;
            mx = fmaxf(mx, m2);
            st += tv;
            stt += tv * tv;
        }
    }
    for (int o = 32; o > 0; o >>= 1) {
        sraw += __shfl_down(sraw, o);
        srt  += __shfl_down(srt, o);
        mx    = fmaxf(mx, __shfl_down(mx, o));
        st   += __shfl_down(st, o);
        stt  += __shfl_down(stt, o);
    }
    int w = t >> 6, lane = t & 63;
    if (lane == 0) {
        rbuf[w][0] = sraw; rbuf[w][1] = srt; rbuf[w][2] = mx;
        rbuf[w][3] = st;   rbuf[w][4] = stt;
    }
    __syncthreads();
    if (t == 0) {
        float a0 = 0.f, a1 = 0.f, a2 = 0.f, a3 = 0.f, a4 = 0.f;
        for (int i = 0; i < 4; ++i) {
            a0 += rbuf[i][0]; a1 += rbuf[i][1]; a2 = fmaxf(a2, rbuf[i][2]);
            a3 += rbuf[i][3]; a4 += rbuf[i][4];
        }
        Praw[bd] = a0; Prt[bd] = a1; Pmax[bd] = a2; Pt[bd] = a3; Ptt[bd] = a4;
    }
}

// ---------------------------------------------------------------------------
// loss_k: unchanged from round 1 (verified correct).
// ---------------------------------------------------------------------------
__global__ __launch_bounds__(NTHREADS) void loss_k(const float2* __restrict__ a,
                                                   const float* __restrict__ label,
                                                   const float* __restrict__ Praw,
                                                   const float* __restrict__ Prt,
                                                   const float* __restrict__ Pmax,
                                                   const float* __restrict__ Pt,
                                                   const float* __restrict__ Ptt,
                                                   float* __restrict__ out) {
    __shared__ float rbuf[4][8];
    __shared__ int ibuf[4][4];
    __shared__ int s_first, s_last;
    int tid = threadIdx.x, b = blockIdx.x;
    int w = tid >> 6, lane = tid & 63;

    float sr = 0.f, srt = 0.f, mx = 0.f, st = 0.f, stt = 0.f;
    for (int i = tid; i < N; i += NTHREADS) {
        int idx = b * N + i;
        sr += Praw[idx]; srt += Prt[idx]; mx = fmaxf(mx, Pmax[idx]);
        st += Pt[idx];   stt += Ptt[idx];
    }
    for (int o = 32; o > 0; o >>= 1) {
        sr  += __shfl_down(sr, o);
        srt += __shfl_down(srt, o);
        mx   = fmaxf(mx, __shfl_down(mx, o));
        st  += __shfl_down(st, o);
        stt += __shfl_down(stt, o);
    }
    if (lane == 0) {
        rbuf[w][0] = sr; rbuf[w][1] = srt; rbuf[w][2] = mx;
        rbuf[w][3] = st; rbuf[w][4] = stt;
    }
    __syncthreads();
    float frog = 0.f;
    if (tid == 0) {
        float A0 = 0.f, A1 = 0.f, A2 = 0.f, A3 = 0.f, A4 = 0.f;
        for (int i = 0; i < 4; ++i) {
            A0 += rbuf[i][0]; A1 += rbuf[i][1]; A2 = fmaxf(A2, rbuf[i][2]);
            A3 += rbuf[i][3]; A4 += rbuf[i][4];
        }
        float mu = (A1 / A2) / A4;
        float diff = A0 / A2 - mu * A3;
        frog = fabsf(diff) * (1.f / (float)N);
    }

    int mnR = N, mxR = -1, mnI = N, mxI = -1;
    for (int n = tid; n < N; n += NTHREADS) {
        float lr = label[b * 2 * N + n];
        float li = label[b * 2 * N + N + n];
        if (fabsf(lr) > 0.01f) { mnR = min(mnR, n); mxR = max(mxR, n); }
        if (fabsf(li) > 0.01f) { mnI = min(mnI, n); mxI = max(mxI, n); }
    }
    for (int o = 32; o > 0; o >>= 1) {
        mnR = min(mnR, __shfl_down(mnR, o));
        mxR = max(mxR, __shfl_down(mxR, o));
        mnI = min(mnI, __shfl_down(mnI, o));
        mxI = max(mxI, __shfl_down(mxI, o));
    }
    if (lane == 0) { ibuf[w][0] = mnR; ibuf[w][1] = mxR; ibuf[w][2] = mnI; ibuf[w][3] = mxI; }
    __syncthreads();
    if (tid == 0) {
        int a0 = N, a1 = -1, a2 = N, a3 = -1;
        for (int i = 0; i < 4; ++i) {
            a0 = min(a0, ibuf[i][0]); a1 = max(a1, ibuf[i][1]);
            a2 = min(a2, ibuf[i][2]); a3 = max(a3, ibuf[i][3]);
        }
        int fr   = (a0 == N) ? 0 : a0;
        int lstR = (a1 < 0) ? (N - 1) : a1;
        int fi   = (a2 == N) ? 0 : a2;
        int lstI = (a3 < 0) ? (N - 1) : a3;
        s_first = min(fr, fi);
        s_last  = max(lstR, lstI);
    }
    __syncthreads();
    int first = s_first, last = s_last;

    float m_r = 0.f, m_i = 0.f, m_n = 0.f, m_p = 0.f;
    for (int n = tid; n < N; n += NTHREADS) {
        float2 p = a[b * N + n];
        float lr = label[b * 2 * N + n];
        float li = label[b * 2 * N + N + n];
        bool in = (n >= first) && (n < last);
        float pm  = in ? 10.f : 1.f;
        float phm = in ? 1.f : 0.f;
        float dr = p.x - lr, di = p.y - li;
        float pint = p.x * p.x + p.y * p.y;
        float lint = lr * lr + li * li;
        float dn = pint - lint;
        float dp = atan2f(p.y, p.x) - atan2f(li, lr);
        m_r += dr * dr * pm;
        m_i += di * di * pm;
        m_n += dn * dn * pm;
        m_p += dp * dp * phm;
    }
    for (int o = 32; o > 0; o >>= 1) {
        m_r += __shfl_down(m_r, o);
        m_i += __shfl_down(m_i, o);
        m_n += __shfl_down(m_n, o);
        m_p += __shfl_down(m_p, o);
    }
    if (lane == 0) { rbuf[w][0] = m_r; rbuf[w][1] = m_i; rbuf[w][2] = m_n; rbuf[w][3] = m_p; }
    __syncthreads();
    if (tid == 0) {
        float t0 = 0.f, t1 = 0.f, t2 = 0.f, t3 = 0.f;
        for (int i = 0; i < 4; ++i) {
            t0 += rbuf[i][0]; t1 += rbuf[i][1]; t2 += rbuf[i][2]; t3 += rbuf[i][3];
        }
        float mse = (t0 + t1 + t2 + t3) * (1.f / (float)N) * 0.25f;
        atomicAdd(out, (mse + frog) * (1.f / (float)BATCH));
    }
}

extern "C" void kernel_launch(void* const* d_in, const int* in_sizes, int n_in,
                              void* d_out, int out_size, void* d_ws, size_t ws_size,
                              hipStream_t stream) {
    (void)in_sizes; (void)n_in; (void)out_size; (void)ws_size;
    const float* pred  = (const float*)d_in[0];
    const float* label = (const float*)d_in[1];
    const float* shg   = (const float*)d_in[2];
    float* out = (float*)d_out;

    char* ws = (char*)d_ws;
    float2* a  = (float2*)ws;                                         // B*N complex
    float2* tw = (float2*)(ws + (size_t)BATCH * N * sizeof(float2));  // 512
    float2* sf = (float2*)((char*)tw + 512 * sizeof(float2));         // 1024
    float*  P  = (float*)((char*)sf + 1024 * sizeof(float2));         // 5 * B*N
    float* Praw = P;
    float* Prt  = P + (size_t)BATCH * N;
    float* Pmax = P + 2 * (size_t)BATCH * N;
    float* Pt   = P + 3 * (size_t)BATCH * N;
    float* Ptt  = P + 4 * (size_t)BATCH * N;

    hipMemsetAsync(d_out, 0, sizeof(float), stream);
    init_tables<<<4, 256, 0, stream>>>(tw, sf);
    hilbert_k<<<BATCH, NTHREADS, 0, stream>>>(pred, tw, a);
    shg_k<<<BATCH * N, NTHREADS, 0, stream>>>(a, shg, sf, Praw, Prt, Pmax, Pt, Ptt);
    loss_k<<<BATCH, NTHREADS, 0, stream>>>(a, label, Praw, Prt, Pmax, Pt, Ptt, out);
}

// Round 3
// 296.771 us; speedup vs baseline: 1.4684x; 1.0523x over previous
//
#include <hip/hip_runtime.h>
#include <math.h>

#define N 1024
#define BATCH 32
#define NT 256
// pad one complex per 32 — keeps stride-1 b64 at free 2-way, breaks pow2 strides
#define PADC(i) ((i) + ((i) >> 5))

typedef float2 cf;
__device__ __forceinline__ cf cadd(cf a, cf b){ return make_float2(a.x+b.x, a.y+b.y); }
__device__ __forceinline__ cf csub(cf a, cf b){ return make_float2(a.x-b.x, a.y-b.y); }
__device__ __forceinline__ cf cmul(cf a, cf b){ return make_float2(a.x*b.x - a.y*b.y, a.x*b.y + a.y*b.x); }

// base-4 digit reversal of 4 digits (8-bit) / 5 digits (10-bit):
// __brev reverses bit pairs AND swaps within pairs; fix with adjacent-bit swap.
__device__ __forceinline__ int rev8(int q){
    int r = (int)(__brev((unsigned)q) >> 24);
    return ((r & 0x55) << 1) | ((r >> 1) & 0x55);
}
__device__ __forceinline__ int rev10(int m){
    int r = (int)(__brev((unsigned)m) >> 22);
    return ((r & 0x155) << 1) | ((r >> 1) & 0x155);
}

// ---------------------------------------------------------------------------
// In-place radix-4 DIF stage, block size n = 1<<LOG2N. One butterfly/thread.
// Reads and writes the same 4 slots (base + q*k). Twiddle after butterfly.
// ---------------------------------------------------------------------------
template<int LOG2N>
__device__ __forceinline__ void dif_stage(cf* w, int t){
    const int n = 1 << LOG2N, q = n >> 2;
    int j = t & (q - 1);
    int base = ((t >> (LOG2N - 2)) << LOG2N) + j;
    cf x0 = w[PADC(base)];
    cf x1 = w[PADC(base + q)];
    cf x2 = w[PADC(base + 2*q)];
    cf x3 = w[PADC(base + 3*q)];
    cf A = cadd(x0,x2), Bs = cadd(x1,x3);
    cf C = csub(x0,x2), D = csub(x1,x3);
    cf Dmi = make_float2(D.y, -D.x);            // -i * D
    cf y0 = cadd(A,Bs), y2 = csub(A,Bs);
    cf y1 = cadd(C,Dmi), y3 = csub(C,Dmi);
    float sn, cs;
    sincospif((float)j * (2.0f / (float)n), &sn, &cs);
    cf w1 = make_float2(cs, -sn);
    cf w2 = cmul(w1,w1);
    cf w3 = cmul(w2,w1);
    w[PADC(base)]       = y0;
    w[PADC(base + q)]   = cmul(y1,w1);
    w[PADC(base + 2*q)] = cmul(y2,w2);
    w[PADC(base + 3*q)] = cmul(y3,w3);
}

// In-place radix-4 DIT stage (twiddle before butterfly); consumes rev-order.
template<int LOG2N>
__device__ __forceinline__ void dit_stage(cf* w, int t){
    const int n = 1 << LOG2N, q = n >> 2;
    int j = t & (q - 1);
    int base = ((t >> (LOG2N - 2)) << LOG2N) + j;
    cf x0 = w[PADC(base)];
    cf x1 = w[PADC(base + q)];
    cf x2 = w[PADC(base + 2*q)];
    cf x3 = w[PADC(base + 3*q)];
    float sn, cs;
    sincospif((float)j * (2.0f / (float)n), &sn, &cs);
    cf w1 = make_float2(cs, -sn);
    cf w2 = cmul(w1,w1);
    cf w3 = cmul(w2,w1);
    x1 = cmul(x1,w1); x2 = cmul(x2,w2); x3 = cmul(x3,w3);
    cf A = cadd(x0,x2), Bs = cadd(x1,x3);
    cf C = csub(x0,x2), D = csub(x1,x3);
    cf Dmi = make_float2(D.y, -D.x);
    w[PADC(base)]       = cadd(A,Bs);
    w[PADC(base + q)]   = cadd(C,Dmi);
    w[PADC(base + 2*q)] = csub(A,Bs);
    w[PADC(base + 3*q)] = csub(C,Dmi);
}

// ---------------------------------------------------------------------------
// hilbert_k: one block per batch. DIF fwd -> mask*conj (rev domain) -> DIT fwd
// -> conj/N = analytic signal. Then fused label-MSE phases (first/last scan,
// masked real/imag/intensity/phase MSE) -> mseJ[b]. Block 0 also fills sf.
// ---------------------------------------------------------------------------
__global__ __launch_bounds__(NT) void hilbert_k(const float* __restrict__ pred,
                                                const float* __restrict__ label,
                                                cf* __restrict__ a,
                                                cf* __restrict__ sf,
                                                float* __restrict__ mseJ) {
    __shared__ cf wk[1056];
    __shared__ float rbuf[4][4];
    __shared__ int ibuf[4][4];
    __shared__ int s_first, s_last;
    int t = threadIdx.x, b = blockIdx.x;
    if (b == 0) {
        for (int i = t; i < N; i += NT) {
            float p = (float)(3.525 * (double)(i - 512));
            float s_, c_;
            sincosf(p, &s_, &c_);
            sf[i] = make_float2(c_, -s_);
        }
    }
    for (int i = t; i < N; i += NT) wk[PADC(i)] = make_float2(pred[b * N + i], 0.f);
    __syncthreads();
    dif_stage<10>(wk, t); __syncthreads();
    dif_stage<8>(wk, t);  __syncthreads();
    dif_stage<6>(wk, t);  __syncthreads();
    dif_stage<4>(wk, t);  __syncthreads();
    dif_stage<2>(wk, t);  __syncthreads();
    // stored[m] = F[rev10(m)]; apply Hilbert mask on bin k, conj for inverse
    for (int i = t; i < N; i += NT) {
        int k = rev10(i);
        float f = (k < 512) ? 0.f : ((k == 512) ? 1.f : 2.f);
        cf v = wk[PADC(i)];
        wk[PADC(i)] = make_float2(f * v.x, -f * v.y);
    }
    __syncthreads();
    dit_stage<2>(wk, t);  __syncthreads();
    dit_stage<4>(wk, t);  __syncthreads();
    dit_stage<6>(wk, t);  __syncthreads();
    dit_stage<8>(wk, t);  __syncthreads();
    dit_stage<10>(wk, t); __syncthreads();
    const float sc = 1.f / (float)N;
    for (int i = t; i < N; i += NT) {
        cf v = wk[PADC(i)];
        cf av = make_float2(v.x * sc, -v.y * sc);
        wk[PADC(i)] = av;
        a[b * N + i] = av;
    }
    __syncthreads();

    int w = t >> 6, lane = t & 63;
    // first/last scan
    int mnR = N, mxR = -1, mnI = N, mxI = -1;
    for (int n = t; n < N; n += NT) {
        float lr = label[b * 2 * N + n];
        float li = label[b * 2 * N + N + n];
        if (fabsf(lr) > 0.01f) { mnR = min(mnR, n); mxR = max(mxR, n); }
        if (fabsf(li) > 0.01f) { mnI = min(mnI, n); mxI = max(mxI, n); }
    }
    for (int o = 32; o > 0; o >>= 1) {
        mnR = min(mnR, __shfl_down(mnR, o));
        mxR = max(mxR, __shfl_down(mxR, o));
        mnI = min(mnI, __shfl_down(mnI, o));
        mxI = max(mxI, __shfl_down(mxI, o));
    }
    if (lane == 0) { ibuf[w][0] = mnR; ibuf[w][1] = mxR; ibuf[w][2] = mnI; ibuf[w][3] = mxI; }
    __syncthreads();
    if (t == 0) {
        int a0 = N, a1 = -1, a2 = N, a3 = -1;
        for (int i = 0; i < 4; ++i) {
            a0 = min(a0, ibuf[i][0]); a1 = max(a1, ibuf[i][1]);
            a2 = min(a2, ibuf[i][2]); a3 = max(a3, ibuf[i][3]);
        }
        int fr   = (a0 == N) ? 0 : a0;
        int lstR = (a1 < 0) ? (N - 1) : a1;
        int fi   = (a2 == N) ? 0 : a2;
        int lstI = (a3 < 0) ? (N - 1) : a3;
        s_first = min(fr, fi);
        s_last  = max(lstR, lstI);
    }
    __syncthreads();
    int first = s_first, last = s_last;

    float m_r = 0.f, m_i = 0.f, m_n = 0.f, m_p = 0.f;
    for (int n = t; n < N; n += NT) {
        cf p = wk[PADC(n)];
        float lr = label[b * 2 * N + n];
        float li = label[b * 2 * N + N + n];
        bool in = (n >= first) && (n < last);
        float pm  = in ? 10.f : 1.f;
        float phm = in ? 1.f : 0.f;
        float dr = p.x - lr, di = p.y - li;
        float dn = (p.x * p.x + p.y * p.y) - (lr * lr + li * li);
        float dp = atan2f(p.y, p.x) - atan2f(li, lr);
        m_r += dr * dr * pm;
        m_i += di * di * pm;
        m_n += dn * dn * pm;
        m_p += dp * dp * phm;
    }
    for (int o = 32; o > 0; o >>= 1) {
        m_r += __shfl_down(m_r, o);
        m_i += __shfl_down(m_i, o);
        m_n += __shfl_down(m_n, o);
        m_p += __shfl_down(m_p, o);
    }
    if (lane == 0) { rbuf[w][0] = m_r; rbuf[w][1] = m_i; rbuf[w][2] = m_n; rbuf[w][3] = m_p; }
    __syncthreads();
    if (t == 0) {
        float s = 0.f;
        for (int i = 0; i < 4; ++i) s += rbuf[i][0] + rbuf[i][1] + rbuf[i][2] + rbuf[i][3];
        mseJ[b] = s * (1.f / (float)N) * 0.25f;
    }
}

// ---------------------------------------------------------------------------
// shg_k: one block per (b,d). In-place radix-4 DIF, stage1 fused with row
// product, stage5 fused with reduction; digit-reversed bins paired with tref.
// ---------------------------------------------------------------------------
__global__ __launch_bounds__(NT) void shg_k(const cf* __restrict__ a,
                                            const float* __restrict__ tref,
                                            const cf* __restrict__ sfg,
                                            float* __restrict__ Praw,
                                            float* __restrict__ Prt,
                                            float* __restrict__ Pmax,
                                            float* __restrict__ Pt,
                                            float* __restrict__ Ptt) {
    __shared__ cf sha[N];
    __shared__ cf wk[1056];
    __shared__ float rbuf[4][8];
    int t = threadIdx.x, bd = blockIdx.x;
    int b = bd >> 10, d = bd & 1023, delay = d - 512;
    for (int i = t; i < N; i += NT) sha[i] = a[b * N + i];
    __syncthreads();

    // ---- stage 1 (n=1024, j=t, base=t): inputs on the fly, fftshift folded ----
    {
        cf x[4];
#pragma unroll
        for (int k = 0; k < 4; ++k) {
            int n_ = (t + 256 * k + 512) & 1023;
            cf u = sha[n_];
            cf v = sha[(n_ - delay) & 1023];
            x[k] = cmul(cmul(u, v), sfg[n_]);
        }
        cf A = cadd(x[0],x[2]), Bs = cadd(x[1],x[3]);
        cf C = csub(x[0],x[2]), D = csub(x[1],x[3]);
        cf Dmi = make_float2(D.y, -D.x);
        cf y0 = cadd(A,Bs), y2 = csub(A,Bs);
        cf y1 = cadd(C,Dmi), y3 = csub(C,Dmi);
        float sn, cs;
        sincospif((float)t * (2.0f / 1024.f), &sn, &cs);
        cf w1 = make_float2(cs, -sn);
        cf w2 = cmul(w1,w1);
        cf w3 = cmul(w2,w1);
        wk[PADC(t)]       = y0;
        wk[PADC(t + 256)] = cmul(y1,w1);
        wk[PADC(t + 512)] = cmul(y2,w2);
        wk[PADC(t + 768)] = cmul(y3,w3);
    }
    __syncthreads();
    dif_stage<8>(wk, t); __syncthreads();
    dif_stage<6>(wk, t); __syncthreads();
    dif_stage<4>(wk, t); __syncthreads();

    // ---- stage 5 (n=4, unit twiddles) fused with reduction ----
    float sraw = 0.f, srt = 0.f, mx = 0.f, st = 0.f, stt = 0.f;
    const float* trow = tref + ((size_t)bd << 10);
    {
        int base = 4 * t;
        cf x0 = wk[PADC(base)], x1 = wk[PADC(base+1)];
        cf x2 = wk[PADC(base+2)], x3 = wk[PADC(base+3)];
        cf A = cadd(x0,x2), Bs = cadd(x1,x3);
        cf C = csub(x0,x2), D = csub(x1,x3);
        cf Dmi = make_float2(D.y, -D.x);
        cf y[4];
        y[0] = cadd(A,Bs); y[1] = cadd(C,Dmi); y[2] = csub(A,Bs); y[3] = csub(C,Dmi);
        int rq = rev8(t);   // stored[4t+m] = F[(m<<8) + rq]
#pragma unroll
        for (int m = 0; m < 4; ++m) {
            float m2 = y[m].x * y[m].x + y[m].y * y[m].y;
            float tv = trow[(((m + 2) & 3) << 8) + rq];  // (bin+512)&1023
            sraw += m2;
            srt += m2 * tv;
            mx = fmaxf(mx, m2);
            st += tv;
            stt += tv * tv;
        }
    }
    for (int o = 32; o > 0; o >>= 1) {
        sraw += __shfl_down(sraw, o);
        srt  += __shfl_down(srt, o);
        mx    = fmaxf(mx, __shfl_down(mx, o));
        st   += __shfl_down(st, o);
        stt  += __shfl_down(stt, o);
    }
    int w = t >> 6, lane = t & 63;
    if (lane == 0) {
        rbuf[w][0] = sraw; rbuf[w][1] = srt; rbuf[w][2] = mx;
        rbuf[w][3] = st;   rbuf[w][4] = stt;
    }
    __syncthreads();
    if (t == 0) {
        float a0 = 0.f, a1 = 0.f, a2 = 0.f, a3 = 0.f, a4 = 0.f;
        for (int i = 0; i < 4; ++i) {
            a0 += rbuf[i][0]; a1 += rbuf[i][1]; a2 = fmaxf(a2, rbuf[i][2]);
            a3 += rbuf[i][3]; a4 += rbuf[i][4];
        }
        Praw[bd] = a0; Prt[bd] = a1; Pmax[bd] = a2; Pt[bd] = a3; Ptt[bd] = a4;
    }
}

// ---------------------------------------------------------------------------
// loss_k: per batch — frog from row partials + mseJ -> atomic mean.
// ---------------------------------------------------------------------------
__global__ __launch_bounds__(NT) void loss_k(const float* __restrict__ Praw,
                                             const float* __restrict__ Prt,
                                             const float* __restrict__ Pmax,
                                             const float* __restrict__ Pt,
                                             const float* __restrict__ Ptt,
                                             const float* __restrict__ mseJ,
                                             float* __restrict__ out) {
    __shared__ float rbuf[4][8];
    int tid = threadIdx.x, b = blockIdx.x;
    int w = tid >> 6, lane = tid & 63;
    float sr = 0.f, srt = 0.f, mx = 0.f, st = 0.f, stt = 0.f;
    for (int i = tid; i < N; i += NT) {
        int idx = b * N + i;
        sr += Praw[idx]; srt += Prt[idx]; mx = fmaxf(mx, Pmax[idx]);
        st += Pt[idx];   stt += Ptt[idx];
    }
    for (int o = 32; o > 0; o >>= 1) {
        sr  += __shfl_down(sr, o);
        srt += __shfl_down(srt, o);
        mx   = fmaxf(mx, __shfl_down(mx, o));
        st  += __shfl_down(st, o);
        stt += __shfl_down(stt, o);
    }
    if (lane == 0) {
        rbuf[w][0] = sr; rbuf[w][1] = srt; rbuf[w][2] = mx;
        rbuf[w][3] = st; rbuf[w][4] = stt;
    }
    __syncthreads();
    if (tid == 0) {
        float A0 = 0.f, A1 = 0.f, A2 = 0.f, A3 = 0.f, A4 = 0.f;
        for (int i = 0; i < 4; ++i) {
            A0 += rbuf[i][0]; A1 += rbuf[i][1]; A2 = fmaxf(A2, rbuf[i][2]);
            A3 += rbuf[i][3]; A4 += rbuf[i][4];
        }
        float mu = (A1 / A2) / A4;
        float diff = A0 / A2 - mu * A3;
        float frog = fabsf(diff) * (1.f / (float)N);
        atomicAdd(out, (mseJ[b] + frog) * (1.f / (float)BATCH));
    }
}

extern "C" void kernel_launch(void* const* d_in, const int* in_sizes, int n_in,
                              void* d_out, int out_size, void* d_ws, size_t ws_size,
                              hipStream_t stream) {
    (void)in_sizes; (void)n_in; (void)out_size; (void)ws_size;
    const float* pred  = (const float*)d_in[0];
    const float* label = (const float*)d_in[1];
    const float* shg   = (const float*)d_in[2];
    float* out = (float*)d_out;

    char* ws = (char*)d_ws;
    cf* a  = (cf*)ws;                                            // B*N complex (256 KB)
    cf* sf = (cf*)(ws + (size_t)BATCH * N * sizeof(cf));         // N complex   (8 KB)
    float* P = (float*)((char*)sf + N * sizeof(cf));             // 5 * B*N     (640 KB)
    float* Praw = P;
    float* Prt  = P + (size_t)BATCH * N;
    float* Pmax = P + 2 * (size_t)BATCH * N;
    float* Pt   = P + 3 * (size_t)BATCH * N;
    float* Ptt  = P + 4 * (size_t)BATCH * N;
    float* mseJ = P + 5 * (size_t)BATCH * N;                     // B floats

    hipMemsetAsync(d_out, 0, sizeof(float), stream);
    hilbert_k<<<BATCH, NT, 0, stream>>>(pred, label, a, sf, mseJ);
    shg_k<<<BATCH * N, NT, 0, stream>>>(a, shg, sf, Praw, Prt, Pmax, Pt, Ptt);
    loss_k<<<BATCH, NT, 0, stream>>>(Praw, Prt, Pmax, Pt, Ptt, mseJ, out);
}